// Round 4
// baseline (3544.957 us; speedup 1.0000x reference)
//
#include <hip/hip_runtime.h>

typedef unsigned short u16;
typedef __bf16 v8bf __attribute__((ext_vector_type(8)));
typedef float  v4f  __attribute__((ext_vector_type(4)));

__device__ __forceinline__ float b2f(u16 h) { return __uint_as_float(((unsigned)h) << 16); }
__device__ __forceinline__ u16 f2b(float f) {
    unsigned u = __float_as_uint(f);
    unsigned r = (u + 0x7FFFu + ((u >> 16) & 1u)) >> 16;  // RNE
    return (u16)r;
}

// ---------------------------------------------------------------------------
// mod3[p][b][j] = sum_k cond[b][k]*mw_p[j][k] + mb_p[j]   (p<3, b<8, j<3072)
__global__ __launch_bounds__(256) void mod_kernel(
    const float* __restrict__ cond,
    const float* __restrict__ mw0, const float* __restrict__ mb0,
    const float* __restrict__ mw1, const float* __restrict__ mb1,
    const float* __restrict__ mw2, const float* __restrict__ mb2,
    float* __restrict__ mod3) {
    const int tid = threadIdx.x, wave = tid >> 6, lane = tid & 63;
    int job = blockIdx.x * 4 + wave;  // 73728 jobs
    int p = job / 24576, r = job % 24576;
    int b = r / 3072, j = r % 3072;
    const float* mw = p == 0 ? mw0 : (p == 1 ? mw1 : mw2);
    const float* mb = p == 0 ? mb0 : (p == 1 ? mb1 : mb2);
    const float4* c = (const float4*)(cond + b * 1024);
    const float4* wr = (const float4*)(mw + (size_t)j * 1024);
    float s = 0.f;
#pragma unroll
    for (int t = 0; t < 4; t++) {
        float4 cv = c[lane + t * 64], wv = wr[lane + t * 64];
        s += cv.x * wv.x + cv.y * wv.y + cv.z * wv.z + cv.w * wv.w;
    }
#pragma unroll
    for (int o = 32; o > 0; o >>= 1) s += __shfl_xor(s, o, 64);
    if (lane == 0) mod3[(size_t)p * 24576 + b * 3072 + j] = s + mb[j];
}

// ---------------------------------------------------------------------------
// AdaRMS: bf16 out = x*rsqrt(mean(x^2)+eps)*w*(1+scale)+shift  (fp32 x,w,mod)
__global__ __launch_bounds__(256) void adarms_kernel(
    const float* __restrict__ Xf, const float* __restrict__ w,
    const float* __restrict__ mod, u16* __restrict__ Out) {
    __shared__ float red[4];
    const int row = blockIdx.x, tid = threadIdx.x;
    const int bidx = row >> 9;
    const float* x = Xf + (size_t)row * 1024;
    float4 v = *(const float4*)(x + tid * 4);
    float s = v.x * v.x + v.y * v.y + v.z * v.z + v.w * v.w;
#pragma unroll
    for (int o = 32; o > 0; o >>= 1) s += __shfl_xor(s, o, 64);
    if ((tid & 63) == 0) red[tid >> 6] = s;
    __syncthreads();
    float tot = red[0] + red[1] + red[2] + red[3];
    float norm = 1.0f / sqrtf(tot * (1.f / 1024.f) + 1e-6f);
    const float* mo = mod + (size_t)bidx * 3072;
    int d = tid * 4;
    float4 wv = *(const float4*)(w + d);
    const float xv[4] = {v.x, v.y, v.z, v.w};
    const float wa[4] = {wv.x, wv.y, wv.z, wv.w};
    u16 o4[4];
#pragma unroll
    for (int t = 0; t < 4; t++) {
        float sc = mo[d + t], sh = mo[1024 + d + t];
        o4[t] = f2b(xv[t] * norm * wa[t] * (1.f + sc) + sh);
    }
    *(ushort4*)(Out + (size_t)row * 1024 + d) = make_ushort4(o4[0], o4[1], o4[2], o4[3]);
}

// ---------------------------------------------------------------------------
// Staging 128 rows x 32 k into LDS as bf16.
// bf16 source: async global_load_lds width=16 (validated bit-exact r2==r3).
// fp32 source: vectorized load + convert + ds_write.
template <typename T>
__device__ __forceinline__ void stage_tile(const T* __restrict__ G, int ldg, int row0,
                                           int k0, u16* lds, int tid) {
    if constexpr (sizeof(T) == 2) {
        const int wave = tid >> 6, lane = tid & 63;
        const int r4 = lane >> 2, c8 = (lane & 3) * 8;
#pragma unroll
        for (int i = 0; i < 2; i++) {
            int row = wave * 32 + i * 16;
            __builtin_amdgcn_global_load_lds(
                (__attribute__((address_space(1))) void*)((const u16*)G + (size_t)(row0 + row + r4) * ldg + k0 + c8),
                (__attribute__((address_space(3))) void*)(&lds[row * 32]), 16, 0, 0);
        }
    } else {
        const int row = tid >> 1, col = (tid & 1) * 16;
        const float* src = (const float*)G + (size_t)(row0 + row) * ldg + k0 + col;
        float4 f0 = *(const float4*)(src);
        float4 f1 = *(const float4*)(src + 4);
        float4 f2 = *(const float4*)(src + 8);
        float4 f3 = *(const float4*)(src + 12);
        ushort4* dst = (ushort4*)(&lds[row * 32 + col]);
        dst[0] = make_ushort4(f2b(f0.x), f2b(f0.y), f2b(f0.z), f2b(f0.w));
        dst[1] = make_ushort4(f2b(f1.x), f2b(f1.y), f2b(f1.z), f2b(f1.w));
        dst[2] = make_ushort4(f2b(f2.x), f2b(f2.y), f2b(f2.z), f2b(f2.w));
        dst[3] = make_ushort4(f2b(f3.x), f2b(f3.y), f2b(f3.z), f2b(f3.w));
    }
}

// ---------------------------------------------------------------------------
// GEMM: C(M,N) = A(M,K) @ Bw(N,K)^T, 128x128 tile, BK=32, mfma 16x16x32 bf16.
// Write index: row*ldc + coff + col.
// MODE 0: Cb[idx] = bf16(acc)
// MODE 1: Xf[row*1024+col] += gate[b][col]*acc          (N==1024)
// MODE 2: Cb[idx] = bf16(silu(Cb[idx])*acc)             (FFN up; gate preact in Cb)
// MODE 3: Cf[idx] = Xf[row*1024+col] + gate*acc  (FP32)  (final output, N==1024)
template <typename TA, typename TB, int MODE>
__global__ __launch_bounds__(256) void gemm_bt(
    const TA* __restrict__ A, const TB* __restrict__ Bw,
    u16* __restrict__ Cb, float* __restrict__ Cf,
    float* __restrict__ Xf, const float* __restrict__ mod,
    int M, int N, int K, int ldc, int coff) {
    __shared__ u16 As[128 * 32];
    __shared__ u16 Bs[128 * 32];
    const int tid = threadIdx.x;
    const int wave = tid >> 6, lane = tid & 63;
    const int m0 = blockIdx.y * 128, n0 = blockIdx.x * 128;
    const int wm = (wave >> 1) * 64, wn = (wave & 1) * 64;
    const int kq = lane >> 4, rr = lane & 15;

    v4f acc[4][4];
#pragma unroll
    for (int i = 0; i < 4; i++)
#pragma unroll
        for (int j = 0; j < 4; j++) acc[i][j] = (v4f){0.f, 0.f, 0.f, 0.f};

    for (int k0 = 0; k0 < K; k0 += 32) {
        __syncthreads();  // prior LDS reads complete before overwrite
        stage_tile<TA>(A, K, m0, k0, As, tid);
        stage_tile<TB>(Bw, K, n0, k0, Bs, tid);
        __syncthreads();  // vmcnt+lgkmcnt drained: tiles visible
        v8bf a[4], b[4];
#pragma unroll
        for (int i = 0; i < 4; i++) a[i] = *(const v8bf*)(&As[(wm + i * 16 + rr) * 32 + kq * 8]);
#pragma unroll
        for (int j = 0; j < 4; j++) b[j] = *(const v8bf*)(&Bs[(wn + j * 16 + rr) * 32 + kq * 8]);
#pragma unroll
        for (int i = 0; i < 4; i++)
#pragma unroll
            for (int j = 0; j < 4; j++)
                acc[i][j] = __builtin_amdgcn_mfma_f32_16x16x32_bf16(a[i], b[j], acc[i][j], 0, 0, 0);
    }

    const int quad = lane >> 4, cl = lane & 15;
#pragma unroll
    for (int i = 0; i < 4; i++)
#pragma unroll
        for (int j = 0; j < 4; j++)
#pragma unroll
            for (int r = 0; r < 4; r++) {
                int row = m0 + wm + i * 16 + quad * 4 + r;
                int col = n0 + wn + j * 16 + cl;
                size_t idx = (size_t)row * ldc + coff + col;
                float v = acc[i][j][r];
                if constexpr (MODE == 0) {
                    Cb[idx] = f2b(v);
                } else if constexpr (MODE == 1) {
                    float g = mod[(row >> 9) * 3072 + 2048 + col];
                    Xf[(size_t)row * 1024 + col] += g * v;
                } else if constexpr (MODE == 2) {
                    float gv = b2f(Cb[idx]);
                    float s = gv / (1.f + __expf(-gv));
                    Cb[idx] = f2b(s * v);
                } else {
                    float g = mod[(row >> 9) * 3072 + 2048 + col];
                    Cf[idx] = Xf[(size_t)row * 1024 + col] + g * v;  // fp32 final output
                }
            }
}

// ---------------------------------------------------------------------------
// Flash attention: 4 waves x 8 queries per block; K/V 64-row chunks in LDS.
// grid (Nq/32, H, B). Nq=512, HD=64, scale folded into Q. All bf16 buffers.
__global__ __launch_bounds__(256) void attn_kernel(
    const u16* __restrict__ Q, int ldq,
    const u16* __restrict__ Kp, const u16* __restrict__ Vp, int ldkv,
    u16* __restrict__ Out, int S) {
    __shared__ float Kt[64][65];
    __shared__ float Vt[64][65];
    __shared__ float qs[32][64];
    __shared__ float ps[4][8][64];
    const int tid = threadIdx.x, wave = tid >> 6, lane = tid & 63;
    const int b = blockIdx.z, h = blockIdx.y, q0 = blockIdx.x * 32;
    const int Nq = 512;
    {
        int row = tid >> 3, dc = (tid & 7) * 8;
        uint4 u = *(const uint4*)(Q + (size_t)(b * Nq + q0 + row) * ldq + h * 64 + dc);
        unsigned wd[4] = {u.x, u.y, u.z, u.w};
#pragma unroll
        for (int t = 0; t < 4; t++) {
            qs[row][dc + 2 * t] = b2f((u16)(wd[t] & 0xffff)) * 0.125f;
            qs[row][dc + 2 * t + 1] = b2f((u16)(wd[t] >> 16)) * 0.125f;
        }
    }
    float Oa[8], m[8], l[8], alpha[8];
#pragma unroll
    for (int q = 0; q < 8; q++) { Oa[q] = 0.f; m[q] = -1e30f; l[q] = 0.f; }
    const int qb = wave * 8;

    for (int s0 = 0; s0 < S; s0 += 64) {
        __syncthreads();
#pragma unroll
        for (int i = 0; i < 2; i++) {
            int c = tid + i * 256;
            int row = c >> 3, dc = (c & 7) * 8;
            size_t base = (size_t)(b * S + s0 + row) * ldkv + h * 64 + dc;
            uint4 uk = *(const uint4*)(Kp + base);
            uint4 uv = *(const uint4*)(Vp + base);
            unsigned wk[4] = {uk.x, uk.y, uk.z, uk.w}, wv[4] = {uv.x, uv.y, uv.z, uv.w};
#pragma unroll
            for (int t = 0; t < 4; t++) {
                Kt[row][dc + 2 * t] = b2f((u16)(wk[t] & 0xffff));
                Kt[row][dc + 2 * t + 1] = b2f((u16)(wk[t] >> 16));
                Vt[row][dc + 2 * t] = b2f((u16)(wv[t] & 0xffff));
                Vt[row][dc + 2 * t + 1] = b2f((u16)(wv[t] >> 16));
            }
        }
        __syncthreads();
#pragma unroll
        for (int q = 0; q < 8; q++) {
            const float* qr = qs[qb + q];
            float s = 0.f;
#pragma unroll 8
            for (int d = 0; d < 64; d++) s += qr[d] * Kt[lane][d];
            float mx = s;
#pragma unroll
            for (int o = 32; o > 0; o >>= 1) mx = fmaxf(mx, __shfl_xor(mx, o, 64));
            float mn = fmaxf(m[q], mx);
            float p = __expf(s - mn);
            alpha[q] = __expf(m[q] - mn);
            m[q] = mn;
            float su = p;
#pragma unroll
            for (int o = 32; o > 0; o >>= 1) su += __shfl_xor(su, o, 64);
            l[q] = l[q] * alpha[q] + su;
            ps[wave][q][lane] = p;
        }
#pragma unroll
        for (int q = 0; q < 8; q++) {
            float o = Oa[q] * alpha[q];
            const float* pr = ps[wave][q];
#pragma unroll 8
            for (int j = 0; j < 64; j++) o += pr[j] * Vt[j][lane];
            Oa[q] = o;
        }
    }
#pragma unroll
    for (int q = 0; q < 8; q++)
        Out[(size_t)(b * Nq + q0 + qb + q) * 1024 + h * 64 + lane] = f2b(Oa[q] / l[q]);
}

// ---------------------------------------------------------------------------
extern "C" void kernel_launch(void* const* d_in, const int* in_sizes, int n_in,
                              void* d_out, int out_size, void* d_ws, size_t ws_size,
                              hipStream_t stream) {
    (void)in_sizes; (void)n_in; (void)out_size; (void)ws_size;
    const float* x    = (const float*)d_in[0];
    const float* ctx  = (const float*)d_in[1];
    const float* cond = (const float*)d_in[2];
    const float* n1w = (const float*)d_in[3];  const float* n1mw = (const float*)d_in[4];  const float* n1mb = (const float*)d_in[5];
    const float* n2w = (const float*)d_in[6];  const float* n2mw = (const float*)d_in[7];  const float* n2mb = (const float*)d_in[8];
    const float* n3w = (const float*)d_in[9];  const float* n3mw = (const float*)d_in[10]; const float* n3mb = (const float*)d_in[11];
    const float* saq = (const float*)d_in[12]; const float* sak = (const float*)d_in[13];
    const float* sav = (const float*)d_in[14]; const float* sao = (const float*)d_in[15];
    const float* caq = (const float*)d_in[16]; const float* cak = (const float*)d_in[17];
    const float* cav = (const float*)d_in[18]; const float* cao = (const float*)d_in[19];
    const float* ffg = (const float*)d_in[20]; const float* ffu = (const float*)d_in[21];
    const float* ffd = (const float*)d_in[22];
    float* out = (float*)d_out;  // reference output dtype is float32

    char* ws = (char*)d_ws;
    size_t off = 0;
    auto alloc = [&](size_t bytes) { void* p = ws + off; off += (bytes + 255) & ~(size_t)255; return p; };
    float* xf   = (float*)alloc((size_t)4194304 * 4);   // running x, fp32      16 MB
    u16* normed = (u16*)alloc((size_t)4194304 * 2);     //                       8 MB
    u16* qkv    = (u16*)alloc((size_t)12582912 * 2);    // SA qkv / CA q        24 MB
    u16* kvb    = (u16*)alloc((size_t)33554432 * 2);    // CA kv / FFN hidden   64 MB
    u16* obuf   = (u16*)alloc((size_t)4194304 * 2);     //                       8 MB
    float* mod3 = (float*)alloc((size_t)73728 * 4);     //                      0.3 MB

    hipMemcpyAsync(xf, x, (size_t)4194304 * 4, hipMemcpyDeviceToDevice, stream);
    mod_kernel<<<18432, 256, 0, stream>>>(cond, n1mw, n1mb, n2mw, n2mb, n3mw, n3mb, mod3);

    // ---- self-attention ----
    adarms_kernel<<<4096, 256, 0, stream>>>(xf, n1w, mod3, normed);
    gemm_bt<u16, float, 0><<<dim3(8, 32), 256, 0, stream>>>(normed, saq, qkv, nullptr, nullptr, nullptr, 4096, 1024, 1024, 3072, 0);
    gemm_bt<u16, float, 0><<<dim3(8, 32), 256, 0, stream>>>(normed, sak, qkv, nullptr, nullptr, nullptr, 4096, 1024, 1024, 3072, 1024);
    gemm_bt<u16, float, 0><<<dim3(8, 32), 256, 0, stream>>>(normed, sav, qkv, nullptr, nullptr, nullptr, 4096, 1024, 1024, 3072, 2048);
    attn_kernel<<<dim3(16, 16, 8), 256, 0, stream>>>(qkv, 3072, qkv + 1024, qkv + 2048, 3072, obuf, 512);
    gemm_bt<u16, float, 1><<<dim3(8, 32), 256, 0, stream>>>(obuf, sao, nullptr, nullptr, xf, mod3, 4096, 1024, 1024, 1024, 0);

    // ---- cross-attention ----
    adarms_kernel<<<4096, 256, 0, stream>>>(xf, n2w, mod3 + 24576, normed);
    gemm_bt<u16, float, 0><<<dim3(8, 32), 256, 0, stream>>>(normed, caq, qkv, nullptr, nullptr, nullptr, 4096, 1024, 1024, 1024, 0);
    gemm_bt<float, float, 0><<<dim3(8, 128), 256, 0, stream>>>(ctx, cak, kvb, nullptr, nullptr, nullptr, 16384, 1024, 2048, 2048, 0);
    gemm_bt<float, float, 0><<<dim3(8, 128), 256, 0, stream>>>(ctx, cav, kvb, nullptr, nullptr, nullptr, 16384, 1024, 2048, 2048, 1024);
    attn_kernel<<<dim3(16, 16, 8), 256, 0, stream>>>(qkv, 1024, kvb, kvb + 1024, 2048, obuf, 2048);
    gemm_bt<u16, float, 1><<<dim3(8, 32), 256, 0, stream>>>(obuf, cao, nullptr, nullptr, xf, mod3 + 24576, 4096, 1024, 1024, 1024, 0);

    // ---- SwiGLU MLP ----
    adarms_kernel<<<4096, 256, 0, stream>>>(xf, n3w, mod3 + 49152, normed);
    gemm_bt<u16, float, 0><<<dim3(32, 32), 256, 0, stream>>>(normed, ffg, kvb, nullptr, nullptr, nullptr, 4096, 4096, 1024, 4096, 0);
    gemm_bt<u16, float, 2><<<dim3(32, 32), 256, 0, stream>>>(normed, ffu, kvb, nullptr, nullptr, nullptr, 4096, 4096, 1024, 4096, 0);
    gemm_bt<u16, float, 3><<<dim3(8, 32), 256, 0, stream>>>(kvb, ffd, nullptr, out, xf, mod3 + 49152, 4096, 1024, 4096, 1024, 0);
}

// Round 5
// 1477.947 us; speedup vs baseline: 2.3986x; 2.3986x over previous
//
#include <hip/hip_runtime.h>

typedef unsigned short u16;
typedef __bf16 v8bf __attribute__((ext_vector_type(8)));
typedef float  v4f  __attribute__((ext_vector_type(4)));

__device__ __forceinline__ float b2f(u16 h) { return __uint_as_float(((unsigned)h) << 16); }
__device__ __forceinline__ u16 f2b(float f) {
    unsigned u = __float_as_uint(f);
    unsigned r = (u + 0x7FFFu + ((u >> 16) & 1u)) >> 16;  // RNE
    return (u16)r;
}

// ---------------------------------------------------------------------------
// mod3[p][b][j] = sum_k cond[b][k]*mw_p[j][k] + mb_p[j]   (p<3, b<8, j<3072)
__global__ __launch_bounds__(256) void mod_kernel(
    const float* __restrict__ cond,
    const float* __restrict__ mw0, const float* __restrict__ mb0,
    const float* __restrict__ mw1, const float* __restrict__ mb1,
    const float* __restrict__ mw2, const float* __restrict__ mb2,
    float* __restrict__ mod3) {
    const int tid = threadIdx.x, wave = tid >> 6, lane = tid & 63;
    int job = blockIdx.x * 4 + wave;  // 73728 jobs
    int p = job / 24576, r = job % 24576;
    int b = r / 3072, j = r % 3072;
    const float* mw = p == 0 ? mw0 : (p == 1 ? mw1 : mw2);
    const float* mb = p == 0 ? mb0 : (p == 1 ? mb1 : mb2);
    const float4* c = (const float4*)(cond + b * 1024);
    const float4* wr = (const float4*)(mw + (size_t)j * 1024);
    float s = 0.f;
#pragma unroll
    for (int t = 0; t < 4; t++) {
        float4 cv = c[lane + t * 64], wv = wr[lane + t * 64];
        s += cv.x * wv.x + cv.y * wv.y + cv.z * wv.z + cv.w * wv.w;
    }
#pragma unroll
    for (int o = 32; o > 0; o >>= 1) s += __shfl_xor(s, o, 64);
    if (lane == 0) mod3[(size_t)p * 24576 + b * 3072 + j] = s + mb[j];
}

// ---------------------------------------------------------------------------
// AdaRMS: bf16 out = x*rsqrt(mean(x^2)+eps)*w*(1+scale)+shift  (fp32 x,w,mod)
__global__ __launch_bounds__(256) void adarms_kernel(
    const float* __restrict__ Xf, const float* __restrict__ w,
    const float* __restrict__ mod, u16* __restrict__ Out) {
    __shared__ float red[4];
    const int row = blockIdx.x, tid = threadIdx.x;
    const int bidx = row >> 9;
    const float* x = Xf + (size_t)row * 1024;
    float4 v = *(const float4*)(x + tid * 4);
    float s = v.x * v.x + v.y * v.y + v.z * v.z + v.w * v.w;
#pragma unroll
    for (int o = 32; o > 0; o >>= 1) s += __shfl_xor(s, o, 64);
    if ((tid & 63) == 0) red[tid >> 6] = s;
    __syncthreads();
    float tot = red[0] + red[1] + red[2] + red[3];
    float norm = 1.0f / sqrtf(tot * (1.f / 1024.f) + 1e-6f);
    const float* mo = mod + (size_t)bidx * 3072;
    int d = tid * 4;
    float4 wv = *(const float4*)(w + d);
    const float xv[4] = {v.x, v.y, v.z, v.w};
    const float wa[4] = {wv.x, wv.y, wv.z, wv.w};
    u16 o4[4];
#pragma unroll
    for (int t = 0; t < 4; t++) {
        float sc = mo[d + t], sh = mo[1024 + d + t];
        o4[t] = f2b(xv[t] * norm * wa[t] * (1.f + sc) + sh);
    }
    *(ushort4*)(Out + (size_t)row * 1024 + d) = make_ushort4(o4[0], o4[1], o4[2], o4[3]);
}

// ---------------------------------------------------------------------------
// Staging 128 rows x 32 k into LDS as bf16 (GEMM).
template <typename T>
__device__ __forceinline__ void stage_tile(const T* __restrict__ G, int ldg, int row0,
                                           int k0, u16* lds, int tid) {
    if constexpr (sizeof(T) == 2) {
        const int wave = tid >> 6, lane = tid & 63;
        const int r4 = lane >> 2, c8 = (lane & 3) * 8;
#pragma unroll
        for (int i = 0; i < 2; i++) {
            int row = wave * 32 + i * 16;
            __builtin_amdgcn_global_load_lds(
                (__attribute__((address_space(1))) void*)((const u16*)G + (size_t)(row0 + row + r4) * ldg + k0 + c8),
                (__attribute__((address_space(3))) void*)(&lds[row * 32]), 16, 0, 0);
        }
    } else {
        const int row = tid >> 1, col = (tid & 1) * 16;
        const float* src = (const float*)G + (size_t)(row0 + row) * ldg + k0 + col;
        float4 f0 = *(const float4*)(src);
        float4 f1 = *(const float4*)(src + 4);
        float4 f2 = *(const float4*)(src + 8);
        float4 f3 = *(const float4*)(src + 12);
        ushort4* dst = (ushort4*)(&lds[row * 32 + col]);
        dst[0] = make_ushort4(f2b(f0.x), f2b(f0.y), f2b(f0.z), f2b(f0.w));
        dst[1] = make_ushort4(f2b(f1.x), f2b(f1.y), f2b(f1.z), f2b(f1.w));
        dst[2] = make_ushort4(f2b(f2.x), f2b(f2.y), f2b(f2.z), f2b(f2.w));
        dst[3] = make_ushort4(f2b(f3.x), f2b(f3.y), f2b(f3.z), f2b(f3.w));
    }
}

// ---------------------------------------------------------------------------
// GEMM: C(M,N) = A(M,K) @ Bw(N,K)^T, 128x128 tile, BK=32, mfma 16x16x32 bf16.
// MODE 0: Cb[idx] = bf16(acc)
// MODE 1: Xf[row*1024+col] += gate[b][col]*acc
// MODE 2: Cb[idx] = bf16(silu(Cb[idx])*acc)
// MODE 3: Cf[idx] = Xf[row*1024+col] + gate*acc   (fp32 final output)
template <typename TA, typename TB, int MODE>
__global__ __launch_bounds__(256) void gemm_bt(
    const TA* __restrict__ A, const TB* __restrict__ Bw,
    u16* __restrict__ Cb, float* __restrict__ Cf,
    float* __restrict__ Xf, const float* __restrict__ mod,
    int M, int N, int K, int ldc, int coff) {
    __shared__ u16 As[128 * 32];
    __shared__ u16 Bs[128 * 32];
    const int tid = threadIdx.x;
    const int wave = tid >> 6, lane = tid & 63;
    const int m0 = blockIdx.y * 128, n0 = blockIdx.x * 128;
    const int wm = (wave >> 1) * 64, wn = (wave & 1) * 64;
    const int kq = lane >> 4, rr = lane & 15;

    v4f acc[4][4];
#pragma unroll
    for (int i = 0; i < 4; i++)
#pragma unroll
        for (int j = 0; j < 4; j++) acc[i][j] = (v4f){0.f, 0.f, 0.f, 0.f};

    for (int k0 = 0; k0 < K; k0 += 32) {
        __syncthreads();
        stage_tile<TA>(A, K, m0, k0, As, tid);
        stage_tile<TB>(Bw, K, n0, k0, Bs, tid);
        __syncthreads();
        v8bf a[4], b[4];
#pragma unroll
        for (int i = 0; i < 4; i++) a[i] = *(const v8bf*)(&As[(wm + i * 16 + rr) * 32 + kq * 8]);
#pragma unroll
        for (int j = 0; j < 4; j++) b[j] = *(const v8bf*)(&Bs[(wn + j * 16 + rr) * 32 + kq * 8]);
#pragma unroll
        for (int i = 0; i < 4; i++)
#pragma unroll
            for (int j = 0; j < 4; j++)
                acc[i][j] = __builtin_amdgcn_mfma_f32_16x16x32_bf16(a[i], b[j], acc[i][j], 0, 0, 0);
    }

    const int quad = lane >> 4, cl = lane & 15;
#pragma unroll
    for (int i = 0; i < 4; i++)
#pragma unroll
        for (int j = 0; j < 4; j++)
#pragma unroll
            for (int r = 0; r < 4; r++) {
                int row = m0 + wm + i * 16 + quad * 4 + r;
                int col = n0 + wn + j * 16 + cl;
                size_t idx = (size_t)row * ldc + coff + col;
                float v = acc[i][j][r];
                if constexpr (MODE == 0) {
                    Cb[idx] = f2b(v);
                } else if constexpr (MODE == 1) {
                    float g = mod[(row >> 9) * 3072 + 2048 + col];
                    Xf[(size_t)row * 1024 + col] += g * v;
                } else if constexpr (MODE == 2) {
                    float gv = b2f(Cb[idx]);
                    float s = gv / (1.f + __expf(-gv));
                    Cb[idx] = f2b(s * v);
                } else {
                    float g = mod[(row >> 9) * 3072 + 2048 + col];
                    Cf[idx] = Xf[(size_t)row * 1024 + col] + g * v;
                }
            }
}

// ---------------------------------------------------------------------------
// MFMA flash attention. Block = 4 waves; wave w handles 16 queries, one head.
// grid (Nq/64, H, B). S^T = K·Q^T  (C layout: col=q=lane&15, row=kv) so softmax
// stats live per lane&15; O^T = V^T·P^T has the same col=q layout -> alpha
// rescale is lane-local. P routes through per-wave LDS (m120 pattern).
// Ks/Qs use XOR-chunk swizzle (chunk ^= row&7) so b128 frag reads are ~2-way.
// Vs padded to 66 (33-dword stride) so per-lane column reads are conflict-free.
#define ATTN_SCL 0.125f
__global__ __launch_bounds__(256) void attn_kernel(
    const u16* __restrict__ Q, int ldq,
    const u16* __restrict__ Kp, const u16* __restrict__ Vp, int ldkv,
    u16* __restrict__ Out, int S) {
    __shared__ u16 Ks[64 * 64];
    __shared__ u16 Qs[64 * 64];
    __shared__ u16 Vs[64 * 66];
    __shared__ u16 Ps[4][16 * 72];
    const int tid = threadIdx.x, wave = tid >> 6, lane = tid & 63;
    const int b = blockIdx.z, h = blockIdx.y, q0 = blockIdx.x * 64;
    const int Nq = 512;
    const int rr = lane & 15, quad = lane >> 4;
    const int drow = lane >> 3;                  // 0..7 within a 1KB DMA issue
    const int dchunk = (lane & 7) ^ drow;        // swizzled global 16B chunk

    // ---- stage Q tile (64 q x 64 d), swizzled ----
#pragma unroll
    for (int i = 0; i < 2; i++) {
        int r = wave * 16 + i * 8 + drow;
        __builtin_amdgcn_global_load_lds(
            (__attribute__((address_space(1))) void*)(Q + (size_t)(b * Nq + q0 + r) * ldq + h * 64 + dchunk * 8),
            (__attribute__((address_space(3))) void*)(&Qs[(wave * 16 + i * 8) * 64]), 16, 0, 0);
    }
    __syncthreads();  // drains vmcnt: Qs visible

    // hoist Q B-fragments (row = wave*16+rr, k-halves)
    v8bf qf[2];
#pragma unroll
    for (int h2 = 0; h2 < 2; h2++)
        qf[h2] = *(const v8bf*)(&Qs[(wave * 16 + rr) * 64 + (((quad + 4 * h2) ^ (rr & 7)) * 8)]);

    v4f Oa[4];
#pragma unroll
    for (int t = 0; t < 4; t++) Oa[t] = (v4f){0.f, 0.f, 0.f, 0.f};
    float m = -3e38f, l = 0.f;

    for (int s0 = 0; s0 < S; s0 += 64) {
        __syncthreads();  // all waves done reading Ks/Vs of previous chunk
        // stage K (DMA, swizzled)
#pragma unroll
        for (int i = 0; i < 2; i++) {
            int r = wave * 16 + i * 8 + drow;
            __builtin_amdgcn_global_load_lds(
                (__attribute__((address_space(1))) void*)(Kp + (size_t)(b * S + s0 + r) * ldkv + h * 64 + dchunk * 8),
                (__attribute__((address_space(3))) void*)(&Ks[(wave * 16 + i * 8) * 64]), 16, 0, 0);
        }
        // stage V (plain rows, pad 66)
        {
            int vr = tid >> 2, c0 = (tid & 3) * 16;
            const u16* src = Vp + (size_t)(b * S + s0 + vr) * ldkv + h * 64 + c0;
            uint4 u0 = *(const uint4*)(src);
            uint4 u1 = *(const uint4*)(src + 8);
            unsigned* dst = (unsigned*)(&Vs[vr * 66 + c0]);
            dst[0] = u0.x; dst[1] = u0.y; dst[2] = u0.z; dst[3] = u0.w;
            dst[4] = u1.x; dst[5] = u1.y; dst[6] = u1.z; dst[7] = u1.w;
        }
        __syncthreads();  // K DMA + V writes visible

        // ---- S^T = K · Q^T ----
        v4f Sf[4];
#pragma unroll
        for (int t = 0; t < 4; t++) Sf[t] = (v4f){0.f, 0.f, 0.f, 0.f};
#pragma unroll
        for (int t = 0; t < 4; t++)
#pragma unroll
            for (int h2 = 0; h2 < 2; h2++) {
                v8bf kf = *(const v8bf*)(&Ks[(16 * t + rr) * 64 + (((quad + 4 * h2) ^ (rr & 7)) * 8)]);
                Sf[t] = __builtin_amdgcn_mfma_f32_16x16x32_bf16(kf, qf[h2], Sf[t], 0, 0, 0);
            }
        // ---- online softmax over kv (rows) for fixed q (=lane&15) ----
        float mx = -3e38f;
#pragma unroll
        for (int t = 0; t < 4; t++)
#pragma unroll
            for (int r = 0; r < 4; r++) {
                float v = Sf[t][r] * ATTN_SCL;
                Sf[t][r] = v;
                mx = fmaxf(mx, v);
            }
        mx = fmaxf(mx, __shfl_xor(mx, 16, 64));
        mx = fmaxf(mx, __shfl_xor(mx, 32, 64));
        float mn = fmaxf(m, mx);
        float alpha = __expf(m - mn);
        float su = 0.f;
#pragma unroll
        for (int t = 0; t < 4; t++)
#pragma unroll
            for (int r = 0; r < 4; r++) {
                float p = __expf(Sf[t][r] - mn);
                Sf[t][r] = p;
                su += p;
            }
        su += __shfl_xor(su, 16, 64);
        su += __shfl_xor(su, 32, 64);
        l = l * alpha + su;
        m = mn;
#pragma unroll
        for (int t = 0; t < 4; t++)
#pragma unroll
            for (int r = 0; r < 4; r++) Oa[t][r] *= alpha;
        // ---- write P^T frag rows to per-wave LDS as P[q][kv] (bf16) ----
#pragma unroll
        for (int t = 0; t < 4; t++) {
            ushort4 pw = make_ushort4(f2b(Sf[t][0]), f2b(Sf[t][1]), f2b(Sf[t][2]), f2b(Sf[t][3]));
            *(ushort4*)(&Ps[wave][rr * 72 + 16 * t + 4 * quad]) = pw;
        }
        // ---- O^T += V^T · P^T ----
        v8bf pf[2];
#pragma unroll
        for (int h2 = 0; h2 < 2; h2++)
            pf[h2] = *(const v8bf*)(&Ps[wave][rr * 72 + quad * 8 + 32 * h2]);
#pragma unroll
        for (int t = 0; t < 4; t++)
#pragma unroll
            for (int h2 = 0; h2 < 2; h2++) {
                union { v8bf v; u16 e[8]; } vf;
#pragma unroll
                for (int j = 0; j < 8; j++)
                    vf.e[j] = Vs[(quad * 8 + j + 32 * h2) * 66 + 16 * t + rr];
                Oa[t] = __builtin_amdgcn_mfma_f32_16x16x32_bf16(vf.v, pf[h2], Oa[t], 0, 0, 0);
            }
    }
    // ---- epilogue: O^T/l -> staging [q][d] -> coalesced global ----
    float inv = 1.f / l;
#pragma unroll
    for (int t = 0; t < 4; t++) {
        ushort4 ow = make_ushort4(f2b(Oa[t][0] * inv), f2b(Oa[t][1] * inv),
                                  f2b(Oa[t][2] * inv), f2b(Oa[t][3] * inv));
        *(ushort4*)(&Ps[wave][rr * 72 + 16 * t + 4 * quad]) = ow;
    }
#pragma unroll
    for (int j = 0; j < 2; j++) {
        int idx = j * 64 + lane;
        int ql = idx >> 3, c = (idx & 7) * 8;
        uint4 u = *(const uint4*)(&Ps[wave][ql * 72 + c]);
        *(uint4*)(Out + (size_t)(b * Nq + q0 + wave * 16 + ql) * 1024 + h * 64 + c) = u;
    }
}

// ---------------------------------------------------------------------------
extern "C" void kernel_launch(void* const* d_in, const int* in_sizes, int n_in,
                              void* d_out, int out_size, void* d_ws, size_t ws_size,
                              hipStream_t stream) {
    (void)in_sizes; (void)n_in; (void)out_size; (void)ws_size;
    const float* x    = (const float*)d_in[0];
    const float* ctx  = (const float*)d_in[1];
    const float* cond = (const float*)d_in[2];
    const float* n1w = (const float*)d_in[3];  const float* n1mw = (const float*)d_in[4];  const float* n1mb = (const float*)d_in[5];
    const float* n2w = (const float*)d_in[6];  const float* n2mw = (const float*)d_in[7];  const float* n2mb = (const float*)d_in[8];
    const float* n3w = (const float*)d_in[9];  const float* n3mw = (const float*)d_in[10]; const float* n3mb = (const float*)d_in[11];
    const float* saq = (const float*)d_in[12]; const float* sak = (const float*)d_in[13];
    const float* sav = (const float*)d_in[14]; const float* sao = (const float*)d_in[15];
    const float* caq = (const float*)d_in[16]; const float* cak = (const float*)d_in[17];
    const float* cav = (const float*)d_in[18]; const float* cao = (const float*)d_in[19];
    const float* ffg = (const float*)d_in[20]; const float* ffu = (const float*)d_in[21];
    const float* ffd = (const float*)d_in[22];
    float* out = (float*)d_out;  // reference output dtype is float32

    char* ws = (char*)d_ws;
    size_t off = 0;
    auto alloc = [&](size_t bytes) { void* p = ws + off; off += (bytes + 255) & ~(size_t)255; return p; };
    float* xf   = (float*)alloc((size_t)4194304 * 4);   // running x, fp32      16 MB
    u16* normed = (u16*)alloc((size_t)4194304 * 2);     //                       8 MB
    u16* qkv    = (u16*)alloc((size_t)12582912 * 2);    // SA qkv / CA q        24 MB
    u16* kvb    = (u16*)alloc((size_t)33554432 * 2);    // CA kv / FFN hidden   64 MB
    u16* obuf   = (u16*)alloc((size_t)4194304 * 2);     //                       8 MB
    float* mod3 = (float*)alloc((size_t)73728 * 4);     //                      0.3 MB

    hipMemcpyAsync(xf, x, (size_t)4194304 * 4, hipMemcpyDeviceToDevice, stream);
    mod_kernel<<<18432, 256, 0, stream>>>(cond, n1mw, n1mb, n2mw, n2mb, n3mw, n3mb, mod3);

    // ---- self-attention ----
    adarms_kernel<<<4096, 256, 0, stream>>>(xf, n1w, mod3, normed);
    gemm_bt<u16, float, 0><<<dim3(8, 32), 256, 0, stream>>>(normed, saq, qkv, nullptr, nullptr, nullptr, 4096, 1024, 1024, 3072, 0);
    gemm_bt<u16, float, 0><<<dim3(8, 32), 256, 0, stream>>>(normed, sak, qkv, nullptr, nullptr, nullptr, 4096, 1024, 1024, 3072, 1024);
    gemm_bt<u16, float, 0><<<dim3(8, 32), 256, 0, stream>>>(normed, sav, qkv, nullptr, nullptr, nullptr, 4096, 1024, 1024, 3072, 2048);
    attn_kernel<<<dim3(8, 16, 8), 256, 0, stream>>>(qkv, 3072, qkv + 1024, qkv + 2048, 3072, obuf, 512);
    gemm_bt<u16, float, 1><<<dim3(8, 32), 256, 0, stream>>>(obuf, sao, nullptr, nullptr, xf, mod3, 4096, 1024, 1024, 1024, 0);

    // ---- cross-attention ----
    adarms_kernel<<<4096, 256, 0, stream>>>(xf, n2w, mod3 + 24576, normed);
    gemm_bt<u16, float, 0><<<dim3(8, 32), 256, 0, stream>>>(normed, caq, qkv, nullptr, nullptr, nullptr, 4096, 1024, 1024, 1024, 0);
    gemm_bt<float, float, 0><<<dim3(8, 128), 256, 0, stream>>>(ctx, cak, kvb, nullptr, nullptr, nullptr, 16384, 1024, 2048, 2048, 0);
    gemm_bt<float, float, 0><<<dim3(8, 128), 256, 0, stream>>>(ctx, cav, kvb, nullptr, nullptr, nullptr, 16384, 1024, 2048, 2048, 1024);
    attn_kernel<<<dim3(8, 16, 8), 256, 0, stream>>>(qkv, 1024, kvb, kvb + 1024, 2048, obuf, 2048);
    gemm_bt<u16, float, 1><<<dim3(8, 32), 256, 0, stream>>>(obuf, cao, nullptr, nullptr, xf, mod3 + 24576, 4096, 1024, 1024, 1024, 0);

    // ---- SwiGLU MLP ----
    adarms_kernel<<<4096, 256, 0, stream>>>(xf, n3w, mod3 + 49152, normed);
    gemm_bt<u16, float, 0><<<dim3(32, 32), 256, 0, stream>>>(normed, ffg, kvb, nullptr, nullptr, nullptr, 4096, 4096, 1024, 4096, 0);
    gemm_bt<u16, float, 2><<<dim3(32, 32), 256, 0, stream>>>(normed, ffu, kvb, nullptr, nullptr, nullptr, 4096, 4096, 1024, 4096, 0);
    gemm_bt<u16, float, 3><<<dim3(8, 32), 256, 0, stream>>>(kvb, ffd, nullptr, out, xf, mod3 + 49152, 4096, 1024, 4096, 1024, 0);
}